// Round 9
// baseline (268.250 us; speedup 1.0000x reference)
//
#include <hip/hip_runtime.h>
#include <math.h>

#define NB 8192
#define NIN 64
#define NOUT 128
#define NHID 32
#define NEXO 3
#define EXROWS 192
#define NTGT 2

typedef float f32x4 __attribute__((ext_vector_type(4)));
typedef short bf16x8 __attribute__((ext_vector_type(8)));

__device__ __forceinline__ float sigmoidf(float x) {
    return 1.0f / (1.0f + __expf(-x));
}

__device__ __forceinline__ unsigned short f2bf(float x) {   // RNE float->bf16
    unsigned int u = __float_as_uint(x);
    unsigned int r = u + 0x7fffu + ((u >> 16) & 1u);
    return (unsigned short)(r >> 16);
}

// DPP-based cross-lane add (VALU pipe).
template<int CTRL>
__device__ __forceinline__ float dpp_add(float x) {
    int p = __builtin_amdgcn_update_dpp(0, __float_as_int(x), CTRL, 0xf, 0xf, true);
    return x + __int_as_float(p);
}
__device__ __forceinline__ float swz_add_xor16(float x) {   // ds_swizzle xor16
    int p = __builtin_amdgcn_ds_swizzle(__float_as_int(x), 0x401f);
    return x + __int_as_float(p);
}

// -------------------------------------------------------------------------
// Kernel A (MFMA): E[b,i,o] = b1+b3 + out1_exog + out2_exog, written to out.
// (unchanged from round 8)
// -------------------------------------------------------------------------
__global__ __launch_bounds__(256, 4) void narx_exog_kernel(
    const float* __restrict__ exog,
    const float* __restrict__ W1, const float* __restrict__ b1,
    const float* __restrict__ W2, const float* __restrict__ b2,
    const float* __restrict__ W3, const float* __restrict__ b3,
    float* __restrict__ E)
{
    __shared__ __align__(16) float exs[NEXO][EXROWS];
    __shared__ __align__(16) unsigned short exrep[NEXO * 8][200];
    __shared__ __align__(16) unsigned short w2bf[NEXO * 32][72];
    __shared__ __align__(16) float2 w1e2[NEXO][NIN];
    __shared__ __align__(16) float b2l[96];
    __shared__ __align__(16) float w3l[2][96];

    const int tid = threadIdx.x;
    const int b = blockIdx.x;
    const float* exb = exog + (size_t)b * (EXROWS * NEXO);

    for (int idx = tid; idx < EXROWS * NEXO; idx += 256) {
        int t = idx / 3;
        int e = idx - t * 3;
        exs[e][t] = exb[idx];
    }
    for (int idx = tid; idx < 6144; idx += 256) {
        int e = idx >> 11;
        int rem = idx & 2047;
        int u = rem >> 6, t = rem & 63;
        w2bf[e * 32 + u][t] = f2bf(W2[(size_t)(64 + e * 32 + u) * NIN + t]);
    }
    for (int idx = tid; idx < 192; idx += 256) {
        int e = idx >> 6, t = idx & 63;
        w1e2[e][t] = make_float2(W1[t * 5 + 2 + e], W1[320 + t * 5 + 2 + e]);
    }
    if (tid < 96)  b2l[tid] = b2[64 + tid];
    for (int idx = tid; idx < 192; idx += 256) {
        int o = idx / 96, u = idx - o * 96;
        w3l[o][u] = W3[o * 160 + 64 + u];
    }
    __syncthreads();

    for (int idx = tid; idx < NEXO * 8 * 192; idx += 256) {
        int e = idx / 1536;
        int rem = idx - e * 1536;
        int r = rem / 192;
        int q = rem - r * 192;
        float v = (q + r < 192) ? exs[e][q + r] : 0.f;
        exrep[e * 8 + r][q] = f2bf(v);
    }
    __syncthreads();

    const int wv = tid >> 6;
    const int l  = tid & 63;
    const int iw = wv * 32;
    const int lg = l >> 4;
    const int col = l & 15;

    float acc0[2] = {0.f, 0.f};
    float acc1[2] = {0.f, 0.f};

    #pragma unroll 1
    for (int e = 0; e < NEXO; ++e) {
        f32x4 b2v[2], w30v[2], w31v[2];
        #pragma unroll
        for (int mt = 0; mt < 2; ++mt) {
            b2v[mt]  = *(const f32x4*)&b2l[e * 32 + mt * 16 + lg * 4];
            w30v[mt] = *(const f32x4*)&w3l[0][e * 32 + mt * 16 + lg * 4];
            w31v[mt] = *(const f32x4*)&w3l[1][e * 32 + mt * 16 + lg * 4];
        }

        f32x4 cacc[2][2];
        #pragma unroll
        for (int mt = 0; mt < 2; ++mt)
            #pragma unroll
            for (int nt = 0; nt < 2; ++nt)
                cacc[mt][nt] = b2v[mt];

        #pragma unroll
        for (int kt = 0; kt < 2; ++kt) {
            bf16x8 af[2], bfr[2];
            #pragma unroll
            for (int mt = 0; mt < 2; ++mt)
                af[mt] = *(const bf16x8*)&w2bf[e * 32 + mt * 16 + col][kt * 32 + lg * 8];
            #pragma unroll
            for (int nt = 0; nt < 2; ++nt)
                bfr[nt] = *(const bf16x8*)&exrep[e * 8 + (l & 7)]
                              [iw + nt * 16 + kt * 32 + lg * 8 + ((l >> 3) & 1) * 8];
            #pragma unroll
            for (int mt = 0; mt < 2; ++mt)
                #pragma unroll
                for (int nt = 0; nt < 2; ++nt)
                    cacc[mt][nt] = __builtin_amdgcn_mfma_f32_16x16x32_bf16(
                        af[mt], bfr[nt], cacc[mt][nt], 0, 0, 0);
        }

        #pragma unroll
        for (int mt = 0; mt < 2; ++mt)
            #pragma unroll
            for (int nt = 0; nt < 2; ++nt) {
                #pragma unroll
                for (int r = 0; r < 4; ++r) {
                    float sg = sigmoidf(cacc[mt][nt][r]);
                    acc0[nt] += w30v[mt][r] * sg;
                    acc1[nt] += w31v[mt][r] * sg;
                }
            }

        const float* exs_e = &exs[e][0];
        #pragma unroll
        for (int dt = 0; dt < 16; ++dt) {
            float2 wv2 = w1e2[e][lg * 16 + dt];
            float x0 = exs_e[iw + l + dt];
            float x1 = exs_e[iw + 16 + l + dt];
            acc0[0] += wv2.x * x0;
            acc1[0] += wv2.y * x0;
            acc0[1] += wv2.x * x1;
            acc1[1] += wv2.y * x1;
        }
    }

    #pragma unroll
    for (int nt = 0; nt < 2; ++nt) {
        acc0[nt] += __shfl_xor(acc0[nt], 16, 64);
        acc0[nt] += __shfl_xor(acc0[nt], 32, 64);
        acc1[nt] += __shfl_xor(acc1[nt], 16, 64);
        acc1[nt] += __shfl_xor(acc1[nt], 32, 64);
    }
    if (lg == 0) {
        const float bias0 = b1[0] + b3[0];
        const float bias1 = b1[1] + b3[1];
        #pragma unroll
        for (int nt = 0; nt < 2; ++nt) {
            int i = iw + nt * 16 + col;
            *(float2*)&E[(size_t)b * (NOUT * NTGT) + i * 2] =
                make_float2(acc0[nt] + bias0, acc1[nt] + bias1);
        }
    }
}

// -------------------------------------------------------------------------
// Kernel B: recurrence, producer/consumer wave split. Block = 128 threads =
// 2 waves, ONE batch per block. Unit u = lane l (2 series x 32 hidden).
// Wave 0 (producer): taps [0,40)  -> static partial P for chunk c, to LDS.
// Wave 1 (consumer): taps [40,64) -> own static part + P0 + bb, then the 8
// sequential steps (sigmoid, W3/W1 fold, VALU reduce, tail updates).
// Pipeline: producer works chunk c while consumer finishes chunk c-1.
// Per-wave live set ~60-70 regs -> no AGPR copy-spills, high occupancy.
// -------------------------------------------------------------------------
#define CH 8
#define NCH 16

__global__ __launch_bounds__(128) void narx_recur_kernel(
    const float* __restrict__ target,
    const float* __restrict__ W1,
    const float* __restrict__ W2, const float* __restrict__ b2,
    const float* __restrict__ W3,
    float* __restrict__ out)
{
    __shared__ __align__(16) float y[NTGT][200];
    __shared__ __align__(16) float p0buf[2][CH][64];
    __shared__ __align__(16) float e2s[NTGT][NOUT];

    const int tid = threadIdx.x;
    const int wid = tid >> 6;     // 0 = producer, 1 = consumer
    const int l = tid & 63;       // unit index (0..63)
    const int s = l >> 5;         // series
    const int h = l & 31;         // hidden unit
    const int b = blockIdx.x;

    {   // E -> LDS (series-transposed), 128 threads x float2
        float2 ev = *(const float2*)&out[(size_t)b * (NOUT * NTGT) + tid * 2];
        e2s[0][tid] = ev.x;
        e2s[1][tid] = ev.y;
    }
    if (tid < NIN) {   // initial window
        float2 tv = *(const float2*)&target[(size_t)b * (NIN * NTGT) + tid * 2];
        y[0][tid] = tv.x;
        y[1][tid] = tv.y;
    }
    __syncthreads();

    // per-lane weights (paths diverge per wave; liveness keeps footprint low)
    float w2r[40];
    float bb = 0.f, w3own = 0.f, w3oth = 0.f;
    float wo1[2] = {0.f, 0.f}, wo2[2] = {0.f, 0.f};
    if (wid == 0) {
        const float* wr = W2 + (size_t)l * NIN;
        #pragma unroll
        for (int q = 0; q < 10; ++q) {
            float4 v = *(const float4*)(wr + q * 4);
            w2r[q*4+0] = v.x; w2r[q*4+1] = v.y; w2r[q*4+2] = v.z; w2r[q*4+3] = v.w;
        }
    } else {
        const float* wr = W2 + (size_t)l * NIN + 40;
        #pragma unroll
        for (int q = 0; q < 6; ++q) {
            float4 v = *(const float4*)(wr + q * 4);
            w2r[q*4+0] = v.x; w2r[q*4+1] = v.y; w2r[q*4+2] = v.z; w2r[q*4+3] = v.w;
        }
        bb    = b2[l];
        w3own = W3[s * 160 + l];
        w3oth = W3[(1 - s) * 160 + l];
        #pragma unroll
        for (int dt = 0; dt < 2; ++dt) {
            wo1[dt] = W1[s * 320 + (2 * h + dt) * 5 + s];
            wo2[dt] = W1[(1 - s) * 320 + (2 * h + dt) * 5 + s];
        }
    }

    #pragma unroll 1
    for (int it = 0; it <= NCH; ++it) {
        if (wid == 0) {
            if (it < NCH) {
                // ---- producer: static P over taps [0,40) for chunk `it` ----
                const int i0 = it * CH;
                float P[CH];
                #pragma unroll
                for (int j = 0; j < CH; ++j) P[j] = 0.f;
                #pragma unroll
                for (int kq = 0; kq < 12; ++kq) {
                    float4 yv = *(const float4*)&y[s][i0 + kq * 4];
                    #pragma unroll
                    for (int d = 0; d < 4; ++d) {
                        const int k = kq * 4 + d;
                        const float yk = (d == 0) ? yv.x : (d == 1) ? yv.y
                                       : (d == 2) ? yv.z : yv.w;
                        #pragma unroll
                        for (int ci = 0; ci < CH; ++ci) {
                            const int ta = k - ci;
                            if (ta >= 0 && ta < 40) P[ci] += w2r[ta] * yk;
                        }
                    }
                }
                #pragma unroll
                for (int ci = 0; ci < CH; ++ci) p0buf[it & 1][ci][l] = P[ci];
            }
        } else {
            if (it > 0) {
                // ---- consumer: chunk cc = it-1 ----
                const int cc = it - 1;
                const int i0 = cc * CH;
                float P[CH];
                #pragma unroll
                for (int j = 0; j < CH; ++j) P[j] = bb + p0buf[cc & 1][j][l];

                // static part over taps [40,64)
                float ylast = 0.f;
                #pragma unroll
                for (int kq = 0; kq < 6; ++kq) {
                    float4 yv = *(const float4*)&y[s][i0 + 40 + kq * 4];
                    #pragma unroll
                    for (int d = 0; d < 4; ++d) {
                        const int k = 40 + kq * 4 + d;
                        const float yk = (d == 0) ? yv.x : (d == 1) ? yv.y
                                       : (d == 2) ? yv.z : yv.w;
                        #pragma unroll
                        for (int ci = 0; ci < CH; ++ci) {
                            if (k - ci >= 40) P[ci] += w2r[k - ci - 40] * yk;
                        }
                        if (k == 63) ylast = yk;
                    }
                }

                // 8 sequential steps
                float predprev = ylast;
                #pragma unroll
                for (int ci = 0; ci < CH; ++ci) {
                    const int i = i0 + ci;
                    const float y1a = y[s][i + 2 * h];
                    const float y1b = y[s][i + 2 * h + 1];
                    const float ev  = e2s[s][i];

                    const float sg = sigmoidf(P[ci]);
                    float va = w3own * sg + wo1[0] * y1a + wo1[1] * y1b;
                    float vb = w3oth * sg + wo2[0] * y1a + wo2[1] * y1b;

                    auto r = __builtin_amdgcn_permlane32_swap(
                        __float_as_uint(vb), __float_as_uint(vb), false, false);
                    float cc2 = va + (s ? __uint_as_float(r[0]) : __uint_as_float(r[1]));
                    cc2 = swz_add_xor16(cc2);       // xor 16 (LDS swizzle)
                    cc2 = dpp_add<0x128>(cc2);      // xor 8  (row_ror:8)
                    cc2 = dpp_add<0x141>(cc2);      // xor 7  (row_half_mirror)
                    cc2 = dpp_add<0x4E>(cc2);       // xor 2
                    cc2 = dpp_add<0xB1>(cc2);       // xor 1

                    const float pred = cc2 + ev + predprev;
                    #pragma unroll
                    for (int cj = ci + 1; cj < CH; ++cj)
                        P[cj] += w2r[24 - (cj - ci)] * pred;   // taps 57..63
                    if (h == 0) y[s][i + NIN] = pred;
                    predprev = pred;
                }
            }
        }
        __syncthreads();
    }

    {   // dump predictions: thread tid covers output row tid
        float2 ov;
        ov.x = y[0][NIN + tid];
        ov.y = y[1][NIN + tid];
        *(float2*)&out[(size_t)b * (NOUT * NTGT) + tid * 2] = ov;
    }
}

extern "C" void kernel_launch(void* const* d_in, const int* in_sizes, int n_in,
                              void* d_out, int out_size, void* d_ws, size_t ws_size,
                              hipStream_t stream) {
    (void)in_sizes; (void)n_in; (void)out_size; (void)d_ws; (void)ws_size;
    const float* target = (const float*)d_in[0];
    const float* exog   = (const float*)d_in[1];
    const float* W1     = (const float*)d_in[2];
    const float* b1     = (const float*)d_in[3];
    const float* W2     = (const float*)d_in[4];
    const float* b2     = (const float*)d_in[5];
    const float* W3     = (const float*)d_in[6];
    const float* b3     = (const float*)d_in[7];
    float* out = (float*)d_out;

    hipLaunchKernelGGL(narx_exog_kernel, dim3(NB), dim3(256), 0, stream,
                       exog, W1, b1, W2, b2, W3, b3, out);
    hipLaunchKernelGGL(narx_recur_kernel, dim3(NB), dim3(128), 0, stream,
                       target, W1, W2, b2, W3, out);
}

// Round 10
// 254.641 us; speedup vs baseline: 1.0534x; 1.0534x over previous
//
#include <hip/hip_runtime.h>
#include <math.h>

#define NB 8192
#define NIN 64
#define NOUT 128
#define NHID 32
#define NEXO 3
#define EXROWS 192
#define NTGT 2

typedef float f32x2 __attribute__((ext_vector_type(2)));
typedef float f32x4 __attribute__((ext_vector_type(4)));
typedef short bf16x8 __attribute__((ext_vector_type(8)));

__device__ __forceinline__ float sigmoidf(float x) {
    return 1.0f / (1.0f + __expf(-x));
}

__device__ __forceinline__ unsigned short f2bf(float x) {   // RNE float->bf16
    unsigned int u = __float_as_uint(x);
    unsigned int r = u + 0x7fffu + ((u >> 16) & 1u);
    return (unsigned short)(r >> 16);
}

// packed fp32 FMA, src0 = one word of the weight pair broadcast to both halves.
// par (compile-time after unroll) selects lo/hi word of wpair.
__device__ __forceinline__ void pk_fma_bc(f32x2& acc, f32x2 wpair, int par, f32x2 y2) {
    if (par == 0)
        asm("v_pk_fma_f32 %0, %1, %2, %0 op_sel:[0,0,0] op_sel_hi:[0,1,1]"
            : "+v"(acc) : "v"(wpair), "v"(y2));
    else
        asm("v_pk_fma_f32 %0, %1, %2, %0 op_sel:[1,0,0] op_sel_hi:[1,1,1]"
            : "+v"(acc) : "v"(wpair), "v"(y2));
}

// DPP-based cross-lane add (VALU pipe).
template<int CTRL>
__device__ __forceinline__ float dpp_add(float x) {
    int p = __builtin_amdgcn_update_dpp(0, __float_as_int(x), CTRL, 0xf, 0xf, true);
    return x + __int_as_float(p);
}
__device__ __forceinline__ float swz_add_xor16(float x) {   // ds_swizzle xor16
    int p = __builtin_amdgcn_ds_swizzle(__float_as_int(x), 0x401f);
    return x + __int_as_float(p);
}

// -------------------------------------------------------------------------
// Kernel A (MFMA): E[b,i,o] = b1+b3 + out1_exog + out2_exog, written to out.
// (unchanged from rounds 5-9)
// -------------------------------------------------------------------------
__global__ __launch_bounds__(256, 4) void narx_exog_kernel(
    const float* __restrict__ exog,
    const float* __restrict__ W1, const float* __restrict__ b1,
    const float* __restrict__ W2, const float* __restrict__ b2,
    const float* __restrict__ W3, const float* __restrict__ b3,
    float* __restrict__ E)
{
    __shared__ __align__(16) float exs[NEXO][EXROWS];
    __shared__ __align__(16) unsigned short exrep[NEXO * 8][200];
    __shared__ __align__(16) unsigned short w2bf[NEXO * 32][72];
    __shared__ __align__(16) float2 w1e2[NEXO][NIN];
    __shared__ __align__(16) float b2l[96];
    __shared__ __align__(16) float w3l[2][96];

    const int tid = threadIdx.x;
    const int b = blockIdx.x;
    const float* exb = exog + (size_t)b * (EXROWS * NEXO);

    for (int idx = tid; idx < EXROWS * NEXO; idx += 256) {
        int t = idx / 3;
        int e = idx - t * 3;
        exs[e][t] = exb[idx];
    }
    for (int idx = tid; idx < 6144; idx += 256) {
        int e = idx >> 11;
        int rem = idx & 2047;
        int u = rem >> 6, t = rem & 63;
        w2bf[e * 32 + u][t] = f2bf(W2[(size_t)(64 + e * 32 + u) * NIN + t]);
    }
    for (int idx = tid; idx < 192; idx += 256) {
        int e = idx >> 6, t = idx & 63;
        w1e2[e][t] = make_float2(W1[t * 5 + 2 + e], W1[320 + t * 5 + 2 + e]);
    }
    if (tid < 96)  b2l[tid] = b2[64 + tid];
    for (int idx = tid; idx < 192; idx += 256) {
        int o = idx / 96, u = idx - o * 96;
        w3l[o][u] = W3[o * 160 + 64 + u];
    }
    __syncthreads();

    for (int idx = tid; idx < NEXO * 8 * 192; idx += 256) {
        int e = idx / 1536;
        int rem = idx - e * 1536;
        int r = rem / 192;
        int q = rem - r * 192;
        float v = (q + r < 192) ? exs[e][q + r] : 0.f;
        exrep[e * 8 + r][q] = f2bf(v);
    }
    __syncthreads();

    const int wv = tid >> 6;
    const int l  = tid & 63;
    const int iw = wv * 32;
    const int lg = l >> 4;
    const int col = l & 15;

    float acc0[2] = {0.f, 0.f};
    float acc1[2] = {0.f, 0.f};

    #pragma unroll 1
    for (int e = 0; e < NEXO; ++e) {
        f32x4 b2v[2], w30v[2], w31v[2];
        #pragma unroll
        for (int mt = 0; mt < 2; ++mt) {
            b2v[mt]  = *(const f32x4*)&b2l[e * 32 + mt * 16 + lg * 4];
            w30v[mt] = *(const f32x4*)&w3l[0][e * 32 + mt * 16 + lg * 4];
            w31v[mt] = *(const f32x4*)&w3l[1][e * 32 + mt * 16 + lg * 4];
        }

        f32x4 cacc[2][2];
        #pragma unroll
        for (int mt = 0; mt < 2; ++mt)
            #pragma unroll
            for (int nt = 0; nt < 2; ++nt)
                cacc[mt][nt] = b2v[mt];

        #pragma unroll
        for (int kt = 0; kt < 2; ++kt) {
            bf16x8 af[2], bfr[2];
            #pragma unroll
            for (int mt = 0; mt < 2; ++mt)
                af[mt] = *(const bf16x8*)&w2bf[e * 32 + mt * 16 + col][kt * 32 + lg * 8];
            #pragma unroll
            for (int nt = 0; nt < 2; ++nt)
                bfr[nt] = *(const bf16x8*)&exrep[e * 8 + (l & 7)]
                              [iw + nt * 16 + kt * 32 + lg * 8 + ((l >> 3) & 1) * 8];
            #pragma unroll
            for (int mt = 0; mt < 2; ++mt)
                #pragma unroll
                for (int nt = 0; nt < 2; ++nt)
                    cacc[mt][nt] = __builtin_amdgcn_mfma_f32_16x16x32_bf16(
                        af[mt], bfr[nt], cacc[mt][nt], 0, 0, 0);
        }

        #pragma unroll
        for (int mt = 0; mt < 2; ++mt)
            #pragma unroll
            for (int nt = 0; nt < 2; ++nt) {
                #pragma unroll
                for (int r = 0; r < 4; ++r) {
                    float sg = sigmoidf(cacc[mt][nt][r]);
                    acc0[nt] += w30v[mt][r] * sg;
                    acc1[nt] += w31v[mt][r] * sg;
                }
            }

        const float* exs_e = &exs[e][0];
        #pragma unroll
        for (int dt = 0; dt < 16; ++dt) {
            float2 wv2 = w1e2[e][lg * 16 + dt];
            float x0 = exs_e[iw + l + dt];
            float x1 = exs_e[iw + 16 + l + dt];
            acc0[0] += wv2.x * x0;
            acc1[0] += wv2.y * x0;
            acc0[1] += wv2.x * x1;
            acc1[1] += wv2.y * x1;
        }
    }

    #pragma unroll
    for (int nt = 0; nt < 2; ++nt) {
        acc0[nt] += __shfl_xor(acc0[nt], 16, 64);
        acc0[nt] += __shfl_xor(acc0[nt], 32, 64);
        acc1[nt] += __shfl_xor(acc1[nt], 16, 64);
        acc1[nt] += __shfl_xor(acc1[nt], 32, 64);
    }
    if (lg == 0) {
        const float bias0 = b1[0] + b3[0];
        const float bias1 = b1[1] + b3[1];
        #pragma unroll
        for (int nt = 0; nt < 2; ++nt) {
            int i = iw + nt * 16 + col;
            *(float2*)&E[(size_t)b * (NOUT * NTGT) + i * 2] =
                make_float2(acc0[nt] + bias0, acc1[nt] + bias1);
        }
    }
}

// -------------------------------------------------------------------------
// Kernel B: recurrence, 2 BATCHES PACKED PER LANE (f32x2) + producer/consumer
// wave split. Block = 128 threads = 2 waves, TWO batches per block.
// All window/E state is batch-interleaved f32x2 -> every dot FMA is one
// v_pk_fma_f32 (weights as aligned pairs, op_sel word-broadcast).
// Wave 0 (producer): taps [0,48) -> static partial P2 for chunk c, to LDS.
// Wave 1 (consumer): taps [48,64) + the 8 sequential steps per chunk.
// -------------------------------------------------------------------------
#define CH 8
#define NCH 16

__global__ __launch_bounds__(128) void narx_recur_kernel(
    const float* __restrict__ target,
    const float* __restrict__ W1,
    const float* __restrict__ W2, const float* __restrict__ b2,
    const float* __restrict__ W3,
    float* __restrict__ out)
{
    __shared__ __align__(16) f32x2 y2[NTGT][200];       // batch-interleaved window
    __shared__ __align__(16) f32x2 p0buf[2][CH][64];
    __shared__ __align__(16) f32x2 e2s[NTGT][NOUT];

    const int tid = threadIdx.x;
    const int wid = tid >> 6;     // 0 = producer, 1 = consumer
    const int l = tid & 63;       // unit index
    const int s = l >> 5;         // series
    const int h = l & 31;         // hidden unit
    const size_t bA = (size_t)blockIdx.x * 2;
    const size_t bB = bA + 1;

    {   // E -> LDS, batch-interleaved; tid covers lag i = tid
        float2 eA = *(const float2*)&out[bA * (NOUT * NTGT) + tid * 2];
        float2 eB = *(const float2*)&out[bB * (NOUT * NTGT) + tid * 2];
        e2s[0][tid] = f32x2{eA.x, eB.x};
        e2s[1][tid] = f32x2{eA.y, eB.y};
    }
    if (tid < NIN) {   // initial window rows
        float2 tA = *(const float2*)&target[bA * (NIN * NTGT) + tid * 2];
        float2 tB = *(const float2*)&target[bB * (NIN * NTGT) + tid * 2];
        y2[0][tid] = f32x2{tA.x, tB.x};
        y2[1][tid] = f32x2{tA.y, tB.y};
    }
    __syncthreads();

    // per-lane weights (wave-divergent paths; small live sets)
    f32x2 w2p[24];                 // producer: taps [0,48) as aligned pairs
    f32x2 w2c[8];                  // consumer: taps [48,64)
    f32x2 bb2 = {0.f, 0.f};
    f32x2 w3own2 = {0.f, 0.f}, w3oth2 = {0.f, 0.f};
    f32x2 wo1a2 = {0.f, 0.f}, wo1b2 = {0.f, 0.f};
    f32x2 wo2a2 = {0.f, 0.f}, wo2b2 = {0.f, 0.f};
    if (wid == 0) {
        const float* wr = W2 + (size_t)l * NIN;
        #pragma unroll
        for (int q = 0; q < 12; ++q) {
            float4 v = *(const float4*)(wr + q * 4);
            w2p[2*q]   = f32x2{v.x, v.y};
            w2p[2*q+1] = f32x2{v.z, v.w};
        }
    } else {
        const float* wr = W2 + (size_t)l * NIN + 48;
        #pragma unroll
        for (int q = 0; q < 4; ++q) {
            float4 v = *(const float4*)(wr + q * 4);
            w2c[2*q]   = f32x2{v.x, v.y};
            w2c[2*q+1] = f32x2{v.z, v.w};
        }
        float bb = b2[l];
        float a  = W3[s * 160 + l];
        float o  = W3[(1 - s) * 160 + l];
        bb2 = f32x2{bb, bb};
        w3own2 = f32x2{a, a};
        w3oth2 = f32x2{o, o};
        float w1a0 = W1[s * 320 + (2 * h) * 5 + s];
        float w1a1 = W1[s * 320 + (2 * h + 1) * 5 + s];
        float w1b0 = W1[(1 - s) * 320 + (2 * h) * 5 + s];
        float w1b1 = W1[(1 - s) * 320 + (2 * h + 1) * 5 + s];
        wo1a2 = f32x2{w1a0, w1a0};
        wo1b2 = f32x2{w1a1, w1a1};
        wo2a2 = f32x2{w1b0, w1b0};
        wo2b2 = f32x2{w1b1, w1b1};
    }

    #pragma unroll 1
    for (int it = 0; it <= NCH; ++it) {
        if (wid == 0) {
            if (it < NCH) {
                // ---- producer: static P2 over taps [0,48) for chunk `it` ----
                const int i0 = it * CH;
                f32x2 P2[CH];
                #pragma unroll
                for (int j = 0; j < CH; ++j) P2[j] = f32x2{0.f, 0.f};
                #pragma unroll
                for (int kq = 0; kq < 14; ++kq) {
                    f32x4 ya = *(const f32x4*)&y2[s][i0 + kq * 4];
                    f32x4 yb = *(const f32x4*)&y2[s][i0 + kq * 4 + 2];
                    f32x2 yk[4];
                    yk[0] = f32x2{ya[0], ya[1]};
                    yk[1] = f32x2{ya[2], ya[3]};
                    yk[2] = f32x2{yb[0], yb[1]};
                    yk[3] = f32x2{yb[2], yb[3]};
                    #pragma unroll
                    for (int d = 0; d < 4; ++d) {
                        const int k = kq * 4 + d;
                        #pragma unroll
                        for (int ci = 0; ci < CH; ++ci) {
                            const int ta = k - ci;
                            if (ta >= 0 && ta < 48)
                                pk_fma_bc(P2[ci], w2p[ta >> 1], ta & 1, yk[d]);
                        }
                    }
                }
                #pragma unroll
                for (int ci = 0; ci < CH; ++ci) p0buf[it & 1][ci][l] = P2[ci];
            }
        } else {
            if (it > 0) {
                // ---- consumer: chunk cc = it-1 ----
                const int cc = it - 1;
                const int i0 = cc * CH;
                f32x2 P2[CH];
                #pragma unroll
                for (int j = 0; j < CH; ++j) P2[j] = p0buf[cc & 1][j][l] + bb2;

                // static part over taps [48,64): rows i0+48 .. i0+63
                f32x2 ylast = {0.f, 0.f};
                #pragma unroll
                for (int kq = 0; kq < 4; ++kq) {
                    f32x4 ya = *(const f32x4*)&y2[s][i0 + 48 + kq * 4];
                    f32x4 yb = *(const f32x4*)&y2[s][i0 + 48 + kq * 4 + 2];
                    f32x2 yk[4];
                    yk[0] = f32x2{ya[0], ya[1]};
                    yk[1] = f32x2{ya[2], ya[3]};
                    yk[2] = f32x2{yb[0], yb[1]};
                    yk[3] = f32x2{yb[2], yb[3]};
                    #pragma unroll
                    for (int d = 0; d < 4; ++d) {
                        const int k = 48 + kq * 4 + d;
                        #pragma unroll
                        for (int ci = 0; ci < CH; ++ci) {
                            const int ta = k - ci;
                            if (ta >= 48)
                                pk_fma_bc(P2[ci], w2c[(ta - 48) >> 1], ta & 1, yk[d]);
                        }
                        if (k == 63) ylast = yk[d];
                    }
                }

                // 8 sequential steps
                f32x2 predprev = ylast;
                #pragma unroll
                for (int ci = 0; ci < CH; ++ci) {
                    const int i = i0 + ci;
                    f32x2 y1a = y2[s][i + 2 * h];
                    f32x2 y1b = y2[s][i + 2 * h + 1];
                    f32x2 ev  = e2s[s][i];

                    f32x2 sg;
                    sg.x = sigmoidf(P2[ci].x);
                    sg.y = sigmoidf(P2[ci].y);
                    f32x2 va = {0.f, 0.f}, vb = {0.f, 0.f};
                    pk_fma_bc(va, w3own2, 0, sg);
                    pk_fma_bc(va, wo1a2, 0, y1a);
                    pk_fma_bc(va, wo1b2, 0, y1b);
                    pk_fma_bc(vb, w3oth2, 0, sg);
                    pk_fma_bc(vb, wo2a2, 0, y1a);
                    pk_fma_bc(vb, wo2b2, 0, y1b);

                    // cross-half fold (VALU) per batch half
                    auto r0 = __builtin_amdgcn_permlane32_swap(
                        __float_as_uint(vb.x), __float_as_uint(vb.x), false, false);
                    auto r1 = __builtin_amdgcn_permlane32_swap(
                        __float_as_uint(vb.y), __float_as_uint(vb.y), false, false);
                    f32x2 cc2;
                    cc2.x = va.x + (s ? __uint_as_float(r0[0]) : __uint_as_float(r0[1]));
                    cc2.y = va.y + (s ? __uint_as_float(r1[0]) : __uint_as_float(r1[1]));
                    cc2.x = swz_add_xor16(cc2.x);  cc2.y = swz_add_xor16(cc2.y);
                    cc2.x = dpp_add<0x128>(cc2.x); cc2.y = dpp_add<0x128>(cc2.y);
                    cc2.x = dpp_add<0x141>(cc2.x); cc2.y = dpp_add<0x141>(cc2.y);
                    cc2.x = dpp_add<0x4E>(cc2.x);  cc2.y = dpp_add<0x4E>(cc2.y);
                    cc2.x = dpp_add<0xB1>(cc2.x);  cc2.y = dpp_add<0xB1>(cc2.y);

                    f32x2 pred = cc2 + ev + predprev;
                    #pragma unroll
                    for (int cj = ci + 1; cj < CH; ++cj) {
                        const int ta = 64 - (cj - ci);   // 57..63
                        pk_fma_bc(P2[cj], w2c[(ta - 48) >> 1], ta & 1, pred);
                    }
                    if (h == 0) y2[s][i + NIN] = pred;
                    predprev = pred;
                }
            }
        }
        __syncthreads();
    }

    {   // dump: tid covers output row i = tid for both batches
        f32x2 p0 = y2[0][NIN + tid];
        f32x2 p1 = y2[1][NIN + tid];
        *(float2*)&out[bA * (NOUT * NTGT) + tid * 2] = make_float2(p0.x, p1.x);
        *(float2*)&out[bB * (NOUT * NTGT) + tid * 2] = make_float2(p0.y, p1.y);
    }
}

extern "C" void kernel_launch(void* const* d_in, const int* in_sizes, int n_in,
                              void* d_out, int out_size, void* d_ws, size_t ws_size,
                              hipStream_t stream) {
    (void)in_sizes; (void)n_in; (void)out_size; (void)d_ws; (void)ws_size;
    const float* target = (const float*)d_in[0];
    const float* exog   = (const float*)d_in[1];
    const float* W1     = (const float*)d_in[2];
    const float* b1     = (const float*)d_in[3];
    const float* W2     = (const float*)d_in[4];
    const float* b2     = (const float*)d_in[5];
    const float* W3     = (const float*)d_in[6];
    const float* b3     = (const float*)d_in[7];
    float* out = (float*)d_out;

    hipLaunchKernelGGL(narx_exog_kernel, dim3(NB), dim3(256), 0, stream,
                       exog, W1, b1, W2, b2, W3, b3, out);
    hipLaunchKernelGGL(narx_recur_kernel, dim3(NB / 2), dim3(128), 0, stream,
                       target, W1, W2, b2, W3, out);
}